// Round 2
// baseline (340.817 us; speedup 1.0000x reference)
//
#include <hip/hip_runtime.h>

// SparseLayer: 100000 independent tiny MLPs, 5 -> 2 -> 2 -> 1, batch 128, fp32.
// HBM traffic model: x 256 MB read + out 51.2 MB write + weights 6.4 MB
// -> ~50 us floor at 6.3 TB/s achievable. Prior best 339.2 us = 925 GB/s
// = 12-15% of achievable -> NOT at the BW roofline; latency/issue-bound theory.
//
// R6 = R5 resubmitted verbatim (two GPUAcquisitionTimeouts in a row; R5 has
// never been measured -- do not stack unverified changes).
//
// R5: consolidate weight loads. net0 is always even, so the two nets'
// weights are contiguous and 16B-aligned in w0/w1/w2:
//   w0: 20 floats  -> 5x float4 (was 10x float2)
//   w1:  8 floats  -> 2x float4 (unchanged)
//   w2:  4 floats  -> 1x float4 (was 2x float2)
// Per-thread VMEM ops: 24 -> 18. x loads (10x float4, coalesced 512B/row
// per half-wave) and nt flags unchanged from the verified R4 kernel.
// Block 256 = 8 thread-groups x 2 nets = 16 nets; grid 100000/16 = 6250.

#define NNETS   100000
#define IFACE   5
#define BATCH   128
#define B4      (BATCH / 4)        // 32 float4 per row
#define NETS_PER_BLOCK 16

typedef float vfloat4 __attribute__((ext_vector_type(4)));
typedef float vfloat2 __attribute__((ext_vector_type(2)));

__device__ __forceinline__ vfloat4 f4fma(float s, vfloat4 v, vfloat4 acc) {
    acc.x = fmaf(s, v.x, acc.x);
    acc.y = fmaf(s, v.y, acc.y);
    acc.z = fmaf(s, v.z, acc.z);
    acc.w = fmaf(s, v.w, acc.w);
    return acc;
}

// Compute one net's 2-2-1 MLP for 4 batch columns held in in0..in4.
// Layer-0 weights row0 = {p0.x,p0.y,p1.x,p1.y,p2.x}, row1 = {p2.y,p3.x,p3.y,p4.x,p4.y}
__device__ __forceinline__ vfloat4 mlp_net(
    vfloat4 in0, vfloat4 in1, vfloat4 in2, vfloat4 in3, vfloat4 in4,
    vfloat2 p0, vfloat2 p1, vfloat2 p2, vfloat2 p3, vfloat2 p4,
    vfloat4 a, vfloat2 c)
{
    vfloat4 h00 = p0.x * in0;
    h00 = f4fma(p0.y, in1, h00);
    h00 = f4fma(p1.x, in2, h00);
    h00 = f4fma(p1.y, in3, h00);
    h00 = f4fma(p2.x, in4, h00);

    vfloat4 h01 = p2.y * in0;
    h01 = f4fma(p3.x, in1, h01);
    h01 = f4fma(p3.y, in2, h01);
    h01 = f4fma(p4.x, in3, h01);
    h01 = f4fma(p4.y, in4, h01);

    vfloat4 h10 = a.x * h00;
    h10 = f4fma(a.y, h01, h10);
    vfloat4 h11 = a.z * h00;
    h11 = f4fma(a.w, h01, h11);

    vfloat4 o = c.x * h10;
    o = f4fma(c.y, h11, o);
    return o;
}

__global__ __launch_bounds__(256) void sparse_mlp_kernel(
    const float* __restrict__ x,   // [NNETS*IFACE, BATCH]
    const float* __restrict__ w0,  // [NNETS, 2, 5]
    const float* __restrict__ w1,  // [NNETS, 2, 2]
    const float* __restrict__ w2,  // [NNETS, 1, 2]
    float* __restrict__ out)       // [NNETS, BATCH]
{
    const int t    = threadIdx.x;
    const int lane = t & 31;                      // float4 column within rows
    const int net0 = blockIdx.x * NETS_PER_BLOCK + (t >> 5) * 2;  // even net
    const int net1 = net0 + 1;

    // ---- issue ALL x loads up front (10 outstanding nt loads/thread) ----
    const vfloat4* xr0 = (const vfloat4*)x + (long)net0 * IFACE * B4 + lane;
    const vfloat4* xr1 = (const vfloat4*)x + (long)net1 * IFACE * B4 + lane;
    vfloat4 a0 = __builtin_nontemporal_load(xr0 + 0 * B4);
    vfloat4 a1 = __builtin_nontemporal_load(xr0 + 1 * B4);
    vfloat4 a2 = __builtin_nontemporal_load(xr0 + 2 * B4);
    vfloat4 a3 = __builtin_nontemporal_load(xr0 + 3 * B4);
    vfloat4 a4 = __builtin_nontemporal_load(xr0 + 4 * B4);
    vfloat4 b0 = __builtin_nontemporal_load(xr1 + 0 * B4);
    vfloat4 b1 = __builtin_nontemporal_load(xr1 + 1 * B4);
    vfloat4 b2 = __builtin_nontemporal_load(xr1 + 2 * B4);
    vfloat4 b3 = __builtin_nontemporal_load(xr1 + 3 * B4);
    vfloat4 b4 = __builtin_nontemporal_load(xr1 + 4 * B4);

    // ---- weight loads, consolidated to float4 (net0 even => 16B aligned) ----
    // w0 for both nets: 20 contiguous floats starting at net0*10.
    const vfloat4* w0p = (const vfloat4*)(w0 + (long)net0 * 10);
    vfloat4 v0 = __builtin_nontemporal_load(w0p + 0);  // p0.x p0.y p1.x p1.y
    vfloat4 v1 = __builtin_nontemporal_load(w0p + 1);  // p2.x p2.y p3.x p3.y
    vfloat4 v2 = __builtin_nontemporal_load(w0p + 2);  // p4.x p4.y q0.x q0.y
    vfloat4 v3 = __builtin_nontemporal_load(w0p + 3);  // q1.x q1.y q2.x q2.y
    vfloat4 v4 = __builtin_nontemporal_load(w0p + 4);  // q3.x q3.y q4.x q4.y
    // w1: 4 floats/net, 16B aligned -> float4 each
    const vfloat4* w1p = (const vfloat4*)w1;
    vfloat4 wa = __builtin_nontemporal_load(w1p + net0);
    vfloat4 wb = __builtin_nontemporal_load(w1p + net1);
    // w2: 2 floats/net; both nets in one float4 (net0 even => 16B aligned)
    const vfloat4* w2p = (const vfloat4*)(w2 + (long)net0 * 2);
    vfloat4 cc = __builtin_nontemporal_load(w2p);

    // ---- unpack (register moves only) ----
    vfloat2 p0 = {v0.x, v0.y}, p1 = {v0.z, v0.w};
    vfloat2 p2 = {v1.x, v1.y}, p3 = {v1.z, v1.w};
    vfloat2 p4 = {v2.x, v2.y};
    vfloat2 q0 = {v2.z, v2.w}, q1 = {v3.x, v3.y};
    vfloat2 q2 = {v3.z, v3.w}, q3 = {v4.x, v4.y};
    vfloat2 q4 = {v4.z, v4.w};
    vfloat2 ca = {cc.x, cc.y}, cb = {cc.z, cc.w};

    // ---- compute both nets ----
    vfloat4 o0 = mlp_net(a0, a1, a2, a3, a4, p0, p1, p2, p3, p4, wa, ca);
    vfloat4 o1 = mlp_net(b0, b1, b2, b3, b4, q0, q1, q2, q3, q4, wb, cb);

    // ---- stores (coalesced float4, nontemporal) ----
    __builtin_nontemporal_store(o0, (vfloat4*)out + (long)net0 * B4 + lane);
    __builtin_nontemporal_store(o1, (vfloat4*)out + (long)net1 * B4 + lane);
}

extern "C" void kernel_launch(void* const* d_in, const int* in_sizes, int n_in,
                              void* d_out, int out_size, void* d_ws, size_t ws_size,
                              hipStream_t stream) {
    const float* x  = (const float*)d_in[0];
    const float* w0 = (const float*)d_in[1];
    const float* w1 = (const float*)d_in[2];
    const float* w2 = (const float*)d_in[3];
    float* out = (float*)d_out;

    dim3 block(256);
    dim3 grid(NNETS / NETS_PER_BLOCK);   // 6250, exact
    sparse_mlp_kernel<<<grid, block, 0, stream>>>(x, w0, w1, w2, out);
}